// Round 1
// baseline (848.860 us; speedup 1.0000x reference)
//
#include <hip/hip_runtime.h>
#include <math.h>

#define E 16
#define D 64
#define H 128
#define R 2            // n-rows per block
#define ROWS (R * E)   // 32 expert-rows per block

// ---------------------------------------------------------------------------
// Prep: Wabc[c][j] = Wa + Wb + Wc  (spec_W1 rows 0..127, 128..255, 256..383)
// ---------------------------------------------------------------------------
__global__ void wabc_prep(const float* __restrict__ specW1, float* __restrict__ wabc) {
    int i = blockIdx.x * blockDim.x + threadIdx.x;
    if (i < H * H) {
        wabc[i] = specW1[i] + specW1[H * H + i] + specW1[2 * H * H + i];
    }
}

__device__ inline float waveReduceSum(float v) {
#pragma unroll
    for (int off = 32; off; off >>= 1) v += __shfl_xor(v, off, 64);
    return v;
}

// ---------------------------------------------------------------------------
// Fused router kernel. Block = 256 threads, handles R=2 rows (n values).
// Thread tiling for GEMM stages: wave wq handles 8 expert-rows, each lane
// handles 2 output features (j0, j0+1). LDS row reads are wave-uniform
// broadcasts (conflict-free), weight reads are coalesced dwordx2.
// ---------------------------------------------------------------------------
template <bool USE_WABC>
__global__ __launch_bounds__(256)
void router_kernel(const float* __restrict__ tokens,
                   const float* __restrict__ encW1, const float* __restrict__ encB1,
                   const float* __restrict__ encW2, const float* __restrict__ encB2,
                   const float* __restrict__ specW1, const float* __restrict__ specB1,
                   const float* __restrict__ specW2,
                   const float* __restrict__ defW1, const float* __restrict__ defB1,
                   const float* __restrict__ defW2, const float* __restrict__ defB2,
                   const int* __restrict__ fiPtr, const int* __restrict__ tkPtr,
                   const float* __restrict__ wabc,
                   float* __restrict__ out, int N) {
    __shared__ float s_h[ROWS * H];     // 16 KB   enc1 output
    __shared__ float s_enc[ROWS * H];   // 16 KB   enc2 output (encoded)
    __shared__ float s_ta[ROWS * H];    // 16 KB   tokens (first 8KB) -> absdelta
    __shared__ float s_glob[R * H];
    __shared__ float s_mabs[R * H];
    __shared__ float s_bias[R * H];
    __shared__ float s_logits[ROWS];
    __shared__ float s_dred[4];

    const int tid   = threadIdx.x;
    const int n0    = blockIdx.x * R;
    const int fi    = fiPtr[0];
    const int lane  = tid & 63;
    const int wq    = tid >> 6;        // wave 0..3
    const int j0    = lane * 2;        // 0..126 even
    const int mbase = wq * 8;          // expert-row block for GEMM stages

    // ---- stage 1: load tokens (ROWS*D = 2048 floats) ----
    {
        const size_t base  = (size_t)n0 * (E * D);
        const size_t total = (size_t)N * (E * D);
        float4* dst = (float4*)s_ta;
#pragma unroll
        for (int it = 0; it < 2; it++) {
            int f = tid + it * 256;
            size_t off = base + (size_t)f * 4;
            float4 v = make_float4(0.f, 0.f, 0.f, 0.f);
            if (off + 3 < total) v = *(const float4*)(tokens + off);
            dst[f] = v;
        }
    }
    __syncthreads();

    // ---- stage 2: enc1  h = relu(tok @ W1 + b1), K=64 ----
    {
        float acc[8][2];
#pragma unroll
        for (int m = 0; m < 8; m++) { acc[m][0] = 0.f; acc[m][1] = 0.f; }
        for (int k = 0; k < D; k += 4) {
            float2 w0 = *(const float2*)(encW1 + (k + 0) * H + j0);
            float2 w1 = *(const float2*)(encW1 + (k + 1) * H + j0);
            float2 w2 = *(const float2*)(encW1 + (k + 2) * H + j0);
            float2 w3 = *(const float2*)(encW1 + (k + 3) * H + j0);
#pragma unroll
            for (int m = 0; m < 8; m++) {
                float4 t = *(const float4*)(s_ta + (mbase + m) * D + k);
                acc[m][0] = fmaf(t.w, w3.x, fmaf(t.z, w2.x, fmaf(t.y, w1.x, fmaf(t.x, w0.x, acc[m][0]))));
                acc[m][1] = fmaf(t.w, w3.y, fmaf(t.z, w2.y, fmaf(t.y, w1.y, fmaf(t.x, w0.y, acc[m][1]))));
            }
        }
        float2 b = *(const float2*)(encB1 + j0);
        __syncthreads();  // ensure all token reads done before overwriting later; cheap
#pragma unroll
        for (int m = 0; m < 8; m++) {
            float2 o;
            o.x = fmaxf(acc[m][0] + b.x, 0.f);
            o.y = fmaxf(acc[m][1] + b.y, 0.f);
            *(float2*)(s_h + (mbase + m) * H + j0) = o;
        }
    }
    __syncthreads();

    // ---- stage 3: enc2  encoded = relu(h @ W2 + b2), K=128 ----
    {
        float acc[8][2];
#pragma unroll
        for (int m = 0; m < 8; m++) { acc[m][0] = 0.f; acc[m][1] = 0.f; }
        for (int k = 0; k < H; k += 4) {
            float2 w0 = *(const float2*)(encW2 + (k + 0) * H + j0);
            float2 w1 = *(const float2*)(encW2 + (k + 1) * H + j0);
            float2 w2 = *(const float2*)(encW2 + (k + 2) * H + j0);
            float2 w3 = *(const float2*)(encW2 + (k + 3) * H + j0);
#pragma unroll
            for (int m = 0; m < 8; m++) {
                float4 t = *(const float4*)(s_h + (mbase + m) * H + k);
                acc[m][0] = fmaf(t.w, w3.x, fmaf(t.z, w2.x, fmaf(t.y, w1.x, fmaf(t.x, w0.x, acc[m][0]))));
                acc[m][1] = fmaf(t.w, w3.y, fmaf(t.z, w2.y, fmaf(t.y, w1.y, fmaf(t.x, w0.y, acc[m][1]))));
            }
        }
        float2 b = *(const float2*)(encB2 + j0);
#pragma unroll
        for (int m = 0; m < 8; m++) {
            float2 o;
            o.x = fmaxf(acc[m][0] + b.x, 0.f);
            o.y = fmaxf(acc[m][1] + b.y, 0.f);
            *(float2*)(s_enc + (mbase + m) * H + j0) = o;
        }
    }
    __syncthreads();

    // ---- stage 4: stats: glob mean, absdelta, mean|delta| ----
    {
        const int r = tid >> 7;     // 0..1
        const int c = tid & 127;
        const float* er = s_enc + (r * E) * H + c;
        float s = 0.f;
#pragma unroll
        for (int e = 0; e < E; e++) s += er[e * H];
        float g  = s * (1.f / 16.f);
        float fc = er[fi * H];
        float ma = 0.f;
#pragma unroll
        for (int e = 0; e < E; e++) {
            float d = er[e * H] - fc;
            float a = fabsf(d);
            s_ta[(r * E + e) * H + c] = a;   // absdelta (overwrites dead token buf)
            ma += a;
        }
        s_glob[r * H + c] = g;
        s_mabs[r * H + c] = ma * (1.f / 16.f);
    }
    __syncthreads();

    // ---- stage 5: per-n bias: spec_b1 - full@Wb - glob@Wc ----
    {
        const int r = tid >> 7;
        const int j = tid & 127;
        float acc = specB1[j];
        const float* fr = s_enc + (r * E + fi) * H;   // full token
        const float* gr = s_glob + r * H;
        for (int c = 0; c < H; c += 4) {
            float4 f4 = *(const float4*)(fr + c);
            float4 g4 = *(const float4*)(gr + c);
            acc -= f4.x * specW1[(H + c + 0) * H + j];
            acc -= f4.y * specW1[(H + c + 1) * H + j];
            acc -= f4.z * specW1[(H + c + 2) * H + j];
            acc -= f4.w * specW1[(H + c + 3) * H + j];
            acc -= g4.x * specW1[(2 * H + c + 0) * H + j];
            acc -= g4.y * specW1[(2 * H + c + 1) * H + j];
            acc -= g4.z * specW1[(2 * H + c + 2) * H + j];
            acc -= g4.w * specW1[(2 * H + c + 3) * H + j];
        }
        s_bias[r * H + j] = acc;
    }
    __syncthreads();

    // ---- stage 6: spec GEMM: spec_h = relu(enc@Wabc + absd@Wd + bias); logits ----
    {
        float acc[8][2];
#pragma unroll
        for (int m = 0; m < 8; m++) { acc[m][0] = 0.f; acc[m][1] = 0.f; }
        const int rr = wq >> 1;  // n-row of this wave
        for (int c = 0; c < H; c += 4) {
            float2 wa0, wa1, wa2, wa3;
            if (USE_WABC) {
                wa0 = *(const float2*)(wabc + (c + 0) * H + j0);
                wa1 = *(const float2*)(wabc + (c + 1) * H + j0);
                wa2 = *(const float2*)(wabc + (c + 2) * H + j0);
                wa3 = *(const float2*)(wabc + (c + 3) * H + j0);
            } else {
#pragma unroll
                for (int t = 0; t < 4; t++) {
                    float2 a0 = *(const float2*)(specW1 + (c + t) * H + j0);
                    float2 a1 = *(const float2*)(specW1 + (H + c + t) * H + j0);
                    float2 a2 = *(const float2*)(specW1 + (2 * H + c + t) * H + j0);
                    float2 s2; s2.x = a0.x + a1.x + a2.x; s2.y = a0.y + a1.y + a2.y;
                    if (t == 0) wa0 = s2; else if (t == 1) wa1 = s2; else if (t == 2) wa2 = s2; else wa3 = s2;
                }
            }
            float2 wd0 = *(const float2*)(specW1 + (3 * H + c + 0) * H + j0);
            float2 wd1 = *(const float2*)(specW1 + (3 * H + c + 1) * H + j0);
            float2 wd2 = *(const float2*)(specW1 + (3 * H + c + 2) * H + j0);
            float2 wd3 = *(const float2*)(specW1 + (3 * H + c + 3) * H + j0);
#pragma unroll
            for (int m = 0; m < 8; m++) {
                float4 ev = *(const float4*)(s_enc + (mbase + m) * H + c);
                float4 av = *(const float4*)(s_ta + (mbase + m) * H + c);
                float a0 = acc[m][0], a1 = acc[m][1];
                a0 = fmaf(ev.x, wa0.x, a0); a0 = fmaf(ev.y, wa1.x, a0);
                a0 = fmaf(ev.z, wa2.x, a0); a0 = fmaf(ev.w, wa3.x, a0);
                a0 = fmaf(av.x, wd0.x, a0); a0 = fmaf(av.y, wd1.x, a0);
                a0 = fmaf(av.z, wd2.x, a0); a0 = fmaf(av.w, wd3.x, a0);
                a1 = fmaf(ev.x, wa0.y, a1); a1 = fmaf(ev.y, wa1.y, a1);
                a1 = fmaf(ev.z, wa2.y, a1); a1 = fmaf(ev.w, wa3.y, a1);
                a1 = fmaf(av.x, wd0.y, a1); a1 = fmaf(av.y, wd1.y, a1);
                a1 = fmaf(av.z, wd2.y, a1); a1 = fmaf(av.w, wd3.y, a1);
                acc[m][0] = a0; acc[m][1] = a1;
            }
        }
        float2 bn = *(const float2*)(s_bias + rr * H + j0);
        float2 w2 = *(const float2*)(specW2 + j0);
#pragma unroll
        for (int m = 0; m < 8; m++) {
            float h0 = fmaxf(acc[m][0] + bn.x, 0.f);
            float h1 = fmaxf(acc[m][1] + bn.y, 0.f);
            float p  = h0 * w2.x + h1 * w2.y;   // spec_b2 dropped: softmax shift-invariant
            p = waveReduceSum(p);
            if (lane == 0) s_logits[mbase + m] = p;
        }
    }
    __syncthreads();

    // ---- stage 7: def head GEMV (K=384 over [full, glob, meanabs]) ----
    {
        const int r = tid >> 7;
        const int j = tid & 127;
        float acc = defB1[j];
        const float* fr = s_enc + (r * E + fi) * H;
        const float* gr = s_glob + r * H;
        const float* mr = s_mabs + r * H;
        for (int c = 0; c < H; c += 4) {
            float4 f4 = *(const float4*)(fr + c);
            acc = fmaf(f4.x, defW1[(c + 0) * H + j], acc);
            acc = fmaf(f4.y, defW1[(c + 1) * H + j], acc);
            acc = fmaf(f4.z, defW1[(c + 2) * H + j], acc);
            acc = fmaf(f4.w, defW1[(c + 3) * H + j], acc);
        }
        for (int c = 0; c < H; c += 4) {
            float4 g4 = *(const float4*)(gr + c);
            acc = fmaf(g4.x, defW1[(H + c + 0) * H + j], acc);
            acc = fmaf(g4.y, defW1[(H + c + 1) * H + j], acc);
            acc = fmaf(g4.z, defW1[(H + c + 2) * H + j], acc);
            acc = fmaf(g4.w, defW1[(H + c + 3) * H + j], acc);
        }
        for (int c = 0; c < H; c += 4) {
            float4 m4 = *(const float4*)(mr + c);
            acc = fmaf(m4.x, defW1[(2 * H + c + 0) * H + j], acc);
            acc = fmaf(m4.y, defW1[(2 * H + c + 1) * H + j], acc);
            acc = fmaf(m4.z, defW1[(2 * H + c + 2) * H + j], acc);
            acc = fmaf(m4.w, defW1[(2 * H + c + 3) * H + j], acc);
        }
        float dh = fmaxf(acc, 0.f);
        float v  = dh * defW2[j];
        v = waveReduceSum(v);
        if (lane == 0) s_dred[wq] = v;
    }
    __syncthreads();

    // ---- stage 8: finalize (2 threads: one per n-row) ----
    if (tid < R && (n0 + tid) < N) {
        const int r = tid;
        const int n = n0 + r;
        // defer prob
        float s = s_dred[2 * r] + s_dred[2 * r + 1] + defB2[0];
        out[(size_t)N * E + n] = 1.f / (1.f + expf(-s));
        // top-k selection (fi excluded; strict > matches lax.top_k tie order)
        int k = tkPtr[0];
        if (k < 1) k = 1;
        if (k > E - 1) k = E - 1;
        unsigned chosen = 0u;
        for (int kk = 0; kk < k; kk++) {
            float bv = -INFINITY;
            int bi = 0;
            for (int e = 0; e < E; e++) {
                if (e == fi || ((chosen >> e) & 1u)) continue;
                float v = s_logits[r * E + e];
                if (v > bv) { bv = v; bi = e; }
            }
            chosen |= (1u << bi);
        }
        float mx = -INFINITY;
        for (int e = 0; e < E; e++)
            if ((chosen >> e) & 1u) { float v = s_logits[r * E + e]; if (v > mx) mx = v; }
        float ssum = 0.f;
        for (int e = 0; e < E; e++)
            if ((chosen >> e) & 1u) ssum += expf(s_logits[r * E + e] - mx);
        float inv = 1.f / ssum;
        for (int e = 0; e < E; e++) {
            float wv = 0.f;
            if ((chosen >> e) & 1u) wv = expf(s_logits[r * E + e] - mx) * inv;
            out[(size_t)n * E + e] = wv;
        }
    }
}

extern "C" void kernel_launch(void* const* d_in, const int* in_sizes, int n_in,
                              void* d_out, int out_size, void* d_ws, size_t ws_size,
                              hipStream_t stream) {
    (void)n_in; (void)out_size;
    const float* tokens = (const float*)d_in[0];
    const float* encW1  = (const float*)d_in[1];
    const float* encB1  = (const float*)d_in[2];
    const float* encW2  = (const float*)d_in[3];
    const float* encB2  = (const float*)d_in[4];
    const float* specW1 = (const float*)d_in[5];
    const float* specB1 = (const float*)d_in[6];
    const float* specW2 = (const float*)d_in[7];
    // d_in[8] = spec_b2 (unused: softmax is shift-invariant)
    const float* defW1  = (const float*)d_in[9];
    const float* defB1  = (const float*)d_in[10];
    const float* defW2  = (const float*)d_in[11];
    const float* defB2  = (const float*)d_in[12];
    const int*   fiPtr  = (const int*)d_in[13];
    const int*   tkPtr  = (const int*)d_in[14];
    float* out = (float*)d_out;

    const int N = in_sizes[0] / (E * D);
    const int grid = (N + R - 1) / R;
    const bool useWs = (d_ws != nullptr) && (ws_size >= (size_t)(H * H * sizeof(float)));

    if (useWs) {
        wabc_prep<<<(H * H + 255) / 256, 256, 0, stream>>>(specW1, (float*)d_ws);
        router_kernel<true><<<grid, 256, 0, stream>>>(
            tokens, encW1, encB1, encW2, encB2, specW1, specB1, specW2,
            defW1, defB1, defW2, defB2, fiPtr, tkPtr, (const float*)d_ws, out, N);
    } else {
        router_kernel<false><<<grid, 256, 0, stream>>>(
            tokens, encW1, encB1, encW2, encB2, specW1, specB1, specW2,
            defW1, defB1, defW2, defB2, fiPtr, tkPtr, nullptr, out, N);
    }
}